// Round 3
// baseline (196.006 us; speedup 1.0000x reference)
//
#include <hip/hip_runtime.h>
#include <hip/hip_bf16.h>

// Embedding gather: out[b,s,:] = weight[token_ids[b,s],:]
// BATCH=4, SEQ=4096, DIM=1024, VOCAB=32000, all float32 output.
// One wave (64 lanes) handles one token row in 4 float4 chunks:
//   64 lanes x 16 B x 4 iters = 4096 B = one row.
// Block = 256 threads = 4 waves = 4 tokens per block -> grid = n_tokens/4.
// Memory-bound: ~64 MiB out writes + <=131 MiB weight reads (LLC-cached).

#define DIM 1024
#define F4_PER_ROW (DIM / 4)   // 256 float4 per row
#define TOKENS_PER_BLOCK 4

__global__ __launch_bounds__(256) void embedding_gather_kernel(
    const int* __restrict__ token_ids,
    const float4* __restrict__ weight,   // [VOCAB, DIM/4]
    float4* __restrict__ out,            // [N_TOKENS, DIM/4]
    int n_tokens)
{
    const int wave = threadIdx.x >> 6;        // 0..3
    const int lane = threadIdx.x & 63;        // 0..63
    const int token_slot = blockIdx.x * TOKENS_PER_BLOCK + wave;
    if (token_slot >= n_tokens) return;

    const int tok = token_ids[token_slot];    // wave-uniform scalar load
    const float4* __restrict__ src = weight + (size_t)tok * F4_PER_ROW;
    float4* __restrict__ dst = out + (size_t)token_slot * F4_PER_ROW;

    // 4 chunks of 64 float4s; independent loads -> compiler can batch
    float4 v0 = src[lane];
    float4 v1 = src[lane + 64];
    float4 v2 = src[lane + 128];
    float4 v3 = src[lane + 192];
    dst[lane]       = v0;
    dst[lane + 64]  = v1;
    dst[lane + 128] = v2;
    dst[lane + 192] = v3;
}

extern "C" void kernel_launch(void* const* d_in, const int* in_sizes, int n_in,
                              void* d_out, int out_size, void* d_ws, size_t ws_size,
                              hipStream_t stream) {
    const int* token_ids = (const int*)d_in[0];       // [4, 4096] int32
    const float4* weight = (const float4*)d_in[1];    // [32000, 1024] f32
    float4* out = (float4*)d_out;                     // [4, 4096, 1024] f32

    const int n_tokens = in_sizes[0];                 // 16384
    dim3 grid((n_tokens + TOKENS_PER_BLOCK - 1) / TOKENS_PER_BLOCK);
    dim3 block(256);
    embedding_gather_kernel<<<grid, block, 0, stream>>>(token_ids, weight, out, n_tokens);
}